// Round 1
// baseline (642.465 us; speedup 1.0000x reference)
//
#include <hip/hip_runtime.h>

#define VQ_D 64
#define VQ_CHUNK 128   // codes staged in LDS per iteration: 128*64*4 = 32 KB

__global__ __launch_bounds__(256, 2) void vq_argmin_kernel(
    const float* __restrict__ x, const float* __restrict__ W,
    float* __restrict__ out, int N, int K)
{
    __shared__ float sW[VQ_CHUNK * VQ_D];   // 32 KB
    __shared__ float sWsq[VQ_CHUNK];

    const int tid = threadIdx.x;
    const int row = blockIdx.x * blockDim.x + tid;
    const int load_row = (row < N) ? row : (N - 1);

    // ---- load this row's f[64] into registers (16 x float4) ----
    float f[VQ_D];
    {
        const float4* xf = reinterpret_cast<const float4*>(x) + (size_t)load_row * (VQ_D / 4);
        #pragma unroll
        for (int i = 0; i < VQ_D / 4; ++i) {
            float4 v = xf[i];
            f[4 * i + 0] = v.x; f[4 * i + 1] = v.y;
            f[4 * i + 2] = v.z; f[4 * i + 3] = v.w;
        }
    }
    float fsq = 0.0f;
    #pragma unroll
    for (int d = 0; d < VQ_D; ++d) fsq = __fmaf_rn(f[d], f[d], fsq);

    float best = 3.4e38f;
    int bidx = 0;

    for (int ck = 0; ck < K; ck += VQ_CHUNK) {
        __syncthreads();
        // ---- stage 128 codes (2048 float4, byte-contiguous per wave) ----
        // and compute w_sq per code via width-16 shuffle reduction:
        // float4 j = tid + 256*i belongs to code (j>>4); lanes 16g..16g+15
        // hold the 16 partials of one code.
        const float4* Wg = reinterpret_cast<const float4*>(W) + (size_t)ck * (VQ_D / 4);
        float4* sW4 = reinterpret_cast<float4*>(sW);
        #pragma unroll
        for (int i = 0; i < (VQ_CHUNK * VQ_D / 4) / 256; ++i) {   // 8 iters
            float4 v = Wg[tid + 256 * i];
            sW4[tid + 256 * i] = v;
            float ss = v.x * v.x + v.y * v.y + v.z * v.z + v.w * v.w;
            ss += __shfl_xor(ss, 1, 16);
            ss += __shfl_xor(ss, 2, 16);
            ss += __shfl_xor(ss, 4, 16);
            ss += __shfl_xor(ss, 8, 16);
            if ((tid & 15) == 0) sWsq[16 * i + (tid >> 4)] = ss;
        }
        __syncthreads();

        // ---- distance + running argmin over this chunk ----
        #pragma unroll 2
        for (int c = 0; c < VQ_CHUNK; ++c) {
            const float* wc = sW + c * VQ_D;   // wave-uniform address -> LDS broadcast
            float d0 = 0.f, d1 = 0.f, d2 = 0.f, d3 = 0.f;
            #pragma unroll
            for (int q = 0; q < VQ_D; q += 4) {
                d0 = __fmaf_rn(f[q + 0], wc[q + 0], d0);
                d1 = __fmaf_rn(f[q + 1], wc[q + 1], d1);
                d2 = __fmaf_rn(f[q + 2], wc[q + 2], d2);
                d3 = __fmaf_rn(f[q + 3], wc[q + 3], d3);
            }
            float dot  = (d0 + d1) + (d2 + d3);
            // matches ref rounding: (f_sq + w_sq) - (2*dot), 2*dot exact, fma rounds once
            float dist = __fmaf_rn(-2.0f, dot, fsq + sWsq[c]);
            // strict < keeps first index on exact tie (jnp.argmin semantics)
            bidx = (dist < best) ? (ck + c) : bidx;
            best = (dist < best) ? dist : best;
        }
    }

    // ---- epilogue: gather codebook row (L2-hot), write both copies + index ----
    if (row < N) {
        const float4* wr = reinterpret_cast<const float4*>(W) + (size_t)bidx * (VQ_D / 4);
        float4* q0 = reinterpret_cast<float4*>(out) + (size_t)row * (VQ_D / 4);
        float4* q1 = reinterpret_cast<float4*>(out + (size_t)N * VQ_D) + (size_t)row * (VQ_D / 4);
        #pragma unroll
        for (int i = 0; i < VQ_D / 4; ++i) {
            float4 v = wr[i];
            q0[i] = v;
            q1[i] = v;
        }
        out[(size_t)2 * N * VQ_D + row] = (float)bidx;
    }
}

extern "C" void kernel_launch(void* const* d_in, const int* in_sizes, int n_in,
                              void* d_out, int out_size, void* d_ws, size_t ws_size,
                              hipStream_t stream)
{
    const float* x = (const float*)d_in[0];
    const float* W = (const float*)d_in[1];
    float* out = (float*)d_out;
    const int N = in_sizes[0] / VQ_D;   // 131072
    const int K = in_sizes[1] / VQ_D;   // 1024
    const int blocks = (N + 255) / 256;
    vq_argmin_kernel<<<blocks, 256, 0, stream>>>(x, W, out, N, K);
}

// Round 2
// 604.065 us; speedup vs baseline: 1.0636x; 1.0636x over previous
//
#include <hip/hip_runtime.h>

#define VQ_D 64
#define VQ_K 1024

// ---- Kernel 1: wsq[c] = sum_d W[c][d]^2  (runs every launch; d_ws is re-poisoned) ----
__global__ __launch_bounds__(256) void vq_wsq_kernel(const float* __restrict__ W,
                                                     float* __restrict__ wsq, int K)
{
    int c = blockIdx.x * blockDim.x + threadIdx.x;
    if (c >= K) return;
    const float4* w4 = reinterpret_cast<const float4*>(W) + (size_t)c * (VQ_D / 4);
    float s0 = 0.f, s1 = 0.f, s2 = 0.f, s3 = 0.f;
    #pragma unroll
    for (int i = 0; i < VQ_D / 4; ++i) {
        float4 v = w4[i];
        s0 = __fmaf_rn(v.x, v.x, s0);
        s1 = __fmaf_rn(v.y, v.y, s1);
        s2 = __fmaf_rn(v.z, v.z, s2);
        s3 = __fmaf_rn(v.w, v.w, s3);
    }
    wsq[c] = (s0 + s1) + (s2 + s3);
}

// ---- Kernel 2: argmin + gather. W read via wave-uniform (scalar) loads: no LDS. ----
__global__ __launch_bounds__(256) void vq_main_kernel(const float* __restrict__ x,
                                                      const float* __restrict__ W,
                                                      const float* __restrict__ wsq,
                                                      float* __restrict__ out,
                                                      int N, int K)
{
    __shared__ int sBidx[256];

    const int tid = threadIdx.x;
    const int row = blockIdx.x * 256 + tid;
    const int lrow = (row < N) ? row : (N - 1);

    // ---- own row into registers ----
    float f[VQ_D];
    {
        const float4* xf = reinterpret_cast<const float4*>(x) + (size_t)lrow * (VQ_D / 4);
        #pragma unroll
        for (int i = 0; i < VQ_D / 4; ++i) {
            float4 v = xf[i];
            f[4 * i + 0] = v.x; f[4 * i + 1] = v.y;
            f[4 * i + 2] = v.z; f[4 * i + 3] = v.w;
        }
    }
    float fsq = 0.f;
    {
        float s0 = 0.f, s1 = 0.f, s2 = 0.f, s3 = 0.f;
        #pragma unroll
        for (int q = 0; q < VQ_D; q += 4) {
            s0 = __fmaf_rn(f[q + 0], f[q + 0], s0);
            s1 = __fmaf_rn(f[q + 1], f[q + 1], s1);
            s2 = __fmaf_rn(f[q + 2], f[q + 2], s2);
            s3 = __fmaf_rn(f[q + 3], f[q + 3], s3);
        }
        fsq = (s0 + s1) + (s2 + s3);
    }

    float best = 3.4e38f;
    int bidx = 0;

    // Inner loop: addresses depend only on the uniform loop counter -> the
    // compiler's divergence analysis promotes W/wsq reads to s_load (SMEM),
    // so the FMAs are v_fmac_f32 v,s,v and neither LDS nor per-lane VMEM
    // traffic exists in the hot loop.
    const float4* __restrict__ W4 = reinterpret_cast<const float4*>(W);
    #pragma unroll 2
    for (int c = 0; c < K; ++c) {
        const float4* wc = W4 + (size_t)c * (VQ_D / 4);
        float d0 = 0.f, d1 = 0.f, d2 = 0.f, d3 = 0.f;
        #pragma unroll
        for (int i = 0; i < VQ_D / 4; ++i) {
            float4 w = wc[i];
            d0 = __fmaf_rn(f[4 * i + 0], w.x, d0);
            d1 = __fmaf_rn(f[4 * i + 1], w.y, d1);
            d2 = __fmaf_rn(f[4 * i + 2], w.z, d2);
            d3 = __fmaf_rn(f[4 * i + 3], w.w, d3);
        }
        float dot = (d0 + d1) + (d2 + d3);
        // ref rounding: (f_sq + w_sq) - 2*dot ; 2*dot exact, one rounded subtract
        float dist = __fmaf_rn(-2.0f, dot, fsq + wsq[c]);
        if (dist < best) { best = dist; bidx = c; }   // strict <: first-index ties
    }

    sBidx[tid] = bidx;
    if (row < N) out[(size_t)2 * N * VQ_D + row] = (float)bidx;   // coalesced index write
    __syncthreads();

    // ---- cooperative, fully-coalesced epilogue ----
    // Block owns 256 rows * 16 float4 = 4096 float4 per output tensor.
    const float4* X4 = reinterpret_cast<const float4*>(x);
    float4* O0 = reinterpret_cast<float4*>(out);
    float4* O1 = reinterpret_cast<float4*>(out) + (size_t)N * (VQ_D / 4);
    const size_t base4 = (size_t)blockIdx.x * 256 * (VQ_D / 4);
    #pragma unroll
    for (int i = 0; i < 16; ++i) {
        int j = i * 256 + tid;              // 0..4095, lane-consecutive
        int rowo = j >> 4;                  // row within block (16 lanes share it)
        int d4 = j & 15;
        size_t gj = base4 + (size_t)j;
        if ((int)(gj >> 4) < N) {
            int idx = sBidx[rowo];          // LDS broadcast per 16-lane group
            float4 w = W4[(size_t)idx * (VQ_D / 4) + d4];  // 256B contiguous gather, L2-hot
            float4 xv = X4[gj];
            float4 o;                        // out0 = x + (q - x): matches ref rounding
            o.x = xv.x + (w.x - xv.x);
            o.y = xv.y + (w.y - xv.y);
            o.z = xv.z + (w.z - xv.z);
            o.w = xv.w + (w.w - xv.w);
            O0[gj] = o;                      // coalesced
            O1[gj] = w;                      // coalesced
        }
    }
}

extern "C" void kernel_launch(void* const* d_in, const int* in_sizes, int n_in,
                              void* d_out, int out_size, void* d_ws, size_t ws_size,
                              hipStream_t stream)
{
    const float* x = (const float*)d_in[0];
    const float* W = (const float*)d_in[1];
    float* out = (float*)d_out;
    float* wsq = (float*)d_ws;              // 4 KB scratch
    const int N = in_sizes[0] / VQ_D;       // 131072
    const int K = in_sizes[1] / VQ_D;       // 1024

    vq_wsq_kernel<<<(K + 255) / 256, 256, 0, stream>>>(W, wsq, K);
    vq_main_kernel<<<(N + 255) / 256, 256, 0, stream>>>(x, W, wsq, out, N, K);
}